// Round 7
// baseline (20.701 us; speedup 1.0000x reference)
//
#include <hip/hip_runtime.h>

typedef float f2 __attribute__((ext_vector_type(2)));
typedef float f4 __attribute__((ext_vector_type(4)));
typedef int   i2 __attribute__((ext_vector_type(2)));

#define HIDDEN 64
#define MASK_FILL -1e9f
#define EPT 2  // edges per thread (more waves -> latency hiding)

// scores = relu([x[row], x[col], edge_attr] @ W1 + b1) . v + c
// v = W2 @ Ws, c = b2.Ws + bs  (folded per-block in prologue)
// k processed in pairs (float2 -> v_pk_fma_f32).
__global__ __launch_bounds__(256) void edge_score_fused(
    const float* __restrict__ x,                 // [N,1]
    const int* __restrict__ edge_index,          // [2,E] int32
    const float* __restrict__ edge_attr,         // [E,2]
    const int* __restrict__ edge_mask,           // [E] int32
    const float* __restrict__ W1,                // [4,64]
    const float* __restrict__ b1,                // [64]
    const float* __restrict__ W2,                // [64,64]
    const float* __restrict__ b2,                // [64]
    const float* __restrict__ Ws,                // [64,1]
    const float* __restrict__ bs,                // [1]
    float* __restrict__ out, int E)
{
    // per k-pair k2: wA=(w0_lo,w0_hi,w1_lo,w1_hi) wB=(w2_lo,w2_hi,w3_lo,w3_hi)
    //               wC=(b_lo,b_hi,v_lo,v_hi)
    __shared__ f4 wA[32], wB[32], wC[32];
    __shared__ float cS;

    const int t = threadIdx.x;

    // ---------- prologue ----------
    // v[k] = W2[k]·Ws : thread t -> row k=t>>2, 16 cols starting 16*(t&3)
    {
        const f4* W2v = reinterpret_cast<const f4*>(W2 + t * 16);
        const int j0 = 16 * (t & 3);
        float p = 0.f;
#pragma unroll
        for (int i = 0; i < 4; ++i) {
            const f4 wv = W2v[i];
            const int j = j0 + 4 * i;
            p = fmaf(wv.x, Ws[j], p);
            p = fmaf(wv.y, Ws[j + 1], p);
            p = fmaf(wv.z, Ws[j + 2], p);
            p = fmaf(wv.w, Ws[j + 3], p);
        }
        p += __shfl_xor(p, 1);
        p += __shfl_xor(p, 2);
        if ((t & 3) == 0) {
            const int k = t >> 2;
            reinterpret_cast<float*>(&wC[k >> 1])[2 + (k & 1)] = p;  // v
        }
    }
    if (t < 32) {
        wA[t] = (f4){W1[2 * t], W1[2 * t + 1], W1[64 + 2 * t], W1[64 + 2 * t + 1]};
        wB[t] = (f4){W1[128 + 2 * t], W1[128 + 2 * t + 1], W1[192 + 2 * t], W1[192 + 2 * t + 1]};
    } else if (t >= 64 && t < 128) {
        // wave 1: c = b2·Ws + bs
        const int l = t - 64;
        float p = b2[l] * Ws[l];
#pragma unroll
        for (int off = 1; off < 64; off <<= 1) p += __shfl_xor(p, off);
        if (l == 0) cS = p + bs[0];
    } else if (t >= 192) {
        const int k = t - 192;  // b1
        reinterpret_cast<float*>(&wC[k >> 1])[k & 1] = b1[k];
    }
    __syncthreads();

    // ---------- main: 2 edges / thread ----------
    const int tid = blockIdx.x * 256 + t;
    const int e = tid * EPT;
    if (e >= E) return;  // E % 2 == 0 -> full pairs

    const i2 rows = __builtin_nontemporal_load(reinterpret_cast<const i2*>(edge_index + e));
    const i2 cols = __builtin_nontemporal_load(reinterpret_cast<const i2*>(edge_index + E + e));
    const i2 mk   = __builtin_nontemporal_load(reinterpret_cast<const i2*>(edge_mask + e));
    const f4 ea   = __builtin_nontemporal_load(reinterpret_cast<const f4*>(edge_attr + 2 * e));

    // gathers (x = 200KB, L2-resident)
    const float xr0 = x[rows.x], xr1 = x[rows.y];
    const float xc0 = x[cols.x], xc1 = x[cols.y];

    const f2 xr0b = {xr0, xr0}, xr1b = {xr1, xr1};
    const f2 xc0b = {xc0, xc0}, xc1b = {xc1, xc1};
    const f2 e00 = {ea.x, ea.x}, e10 = {ea.y, ea.y};
    const f2 e01 = {ea.z, ea.z}, e11 = {ea.w, ea.w};

    const float c = cS;
    const f2 z2 = {0.f, 0.f};
    f2 a0 = {c, 0.f}, a1 = {c, 0.f};

#pragma unroll 4
    for (int k2 = 0; k2 < 32; ++k2) {
        const f4 A = wA[k2];   // broadcast ds_read_b128
        const f4 B = wB[k2];
        const f4 C = wC[k2];
        const f2 w0 = {A.x, A.y}, w1 = {A.z, A.w};
        const f2 w2 = {B.x, B.y}, w3 = {B.z, B.w};
        const f2 bb = {C.x, C.y}, vv = {C.z, C.w};

        f2 h0 = __builtin_elementwise_fma(xr0b, w0, __builtin_elementwise_fma(xc0b, w1,
                __builtin_elementwise_fma(e00, w2, __builtin_elementwise_fma(e10, w3, bb))));
        f2 h1 = __builtin_elementwise_fma(xr1b, w0, __builtin_elementwise_fma(xc1b, w1,
                __builtin_elementwise_fma(e01, w2, __builtin_elementwise_fma(e11, w3, bb))));
        a0 = __builtin_elementwise_fma(__builtin_elementwise_max(h0, z2), vv, a0);
        a1 = __builtin_elementwise_fma(__builtin_elementwise_max(h1, z2), vv, a1);
    }

    f2 res;
    res.x = mk.x ? (a0.x + a0.y) : MASK_FILL;
    res.y = mk.y ? (a1.x + a1.y) : MASK_FILL;
    __builtin_nontemporal_store(res, reinterpret_cast<f2*>(out + e));
}

extern "C" void kernel_launch(void* const* d_in, const int* in_sizes, int n_in,
                              void* d_out, int out_size, void* d_ws, size_t ws_size,
                              hipStream_t stream) {
    const float* x          = (const float*)d_in[0];
    const int*   edge_index = (const int*)d_in[1];
    const float* edge_attr  = (const float*)d_in[2];
    const int*   edge_mask  = (const int*)d_in[3];
    const float* W1 = (const float*)d_in[4];
    const float* b1 = (const float*)d_in[5];
    const float* W2 = (const float*)d_in[6];
    const float* b2 = (const float*)d_in[7];
    const float* Ws = (const float*)d_in[8];
    const float* bs = (const float*)d_in[9];
    float* out = (float*)d_out;

    const int E = out_size;  // 1,000,000
    const int threads = 256;
    const int work = (E + EPT - 1) / EPT;
    const int blocks = (work + threads - 1) / threads;
    edge_score_fused<<<blocks, threads, 0, stream>>>(
        x, edge_index, edge_attr, edge_mask, W1, b1, W2, b2, Ws, bs, out, E);
}